// Round 2
// baseline (397.859 us; speedup 1.0000x reference)
//
#include <hip/hip_runtime.h>

// One workgroup (128 threads, 2 waves) per batch element b.
// v3: the I_out trajectory matmul (80 dots of length 128, was ~40us of
// per-CU LDS-pipe serialization) is replaced by a spike-mask recursion:
//   W@hr[s] = 0.9*(W@hr[s-1]) + 0.1*(W@sp[s]),  sp in {0,1}
// Per-step 64-bit ballot masks are recorded in the hidden loop; C[s][g] =
// sum of w[g][h] over spiking h (expected 15-40 bits, not 128 mults).
// The 20-step J-recursion folds into the 4-lane output chain; J at s=19
// is the free `values` output. W_in is loaded ONCE (update-layout,
// coalesced float4) and held in registers; the I_in row dot is
// reassembled with quad shfl_xor (removes the 32MB HBM refetch seen in
// round 1). LDS drops 13.8KB -> ~6.5KB.

namespace {

constexpr int F = 16;
constexpr int H = 128;
constexpr int G = 4;
constexpr int S = 20;
constexpr int HP = H + 1;   // padded W_out row stride for bit-loop reads

__device__ __forceinline__ float clip3(float x) {
    return fminf(fmaxf(x, -3.0f), 3.0f);
}

__global__ __launch_bounds__(128)
void spiking_critic_kernel(
    const float* __restrict__ energy,
    const float* __restrict__ threat,
    const float* __restrict__ food_visible,
    const int*   __restrict__ goal,
    const int*   __restrict__ prev_goal,
    const float* __restrict__ DA,
    const float* __restrict__ NA,
    const float* __restrict__ reward,
    const float* __restrict__ cls_probs,
    const float* __restrict__ W_in_w,
    const float* __restrict__ W_in_b,
    const float* __restrict__ W_out_w,
    const float* __restrict__ W_out_b,
    const float* __restrict__ hv_in,
    const float* __restrict__ hu_in,
    const float* __restrict__ hrate_in,
    const float* __restrict__ vv_in,
    const float* __restrict__ vu_in,
    const float* __restrict__ vrate_in,
    const float* __restrict__ elig_in,
    const float* __restrict__ elig_out,
    const float* __restrict__ prev_values,
    const float* __restrict__ prev_features,
    const float* __restrict__ noise,
    float* __restrict__ out_values,
    float* __restrict__ out_td,
    float* __restrict__ out_hidden,
    float* __restrict__ out_Win,
    float* __restrict__ out_Wout,
    float* __restrict__ out_ein,
    float* __restrict__ out_eout,
    int nB)
{
    const int b = blockIdx.x;
    const int t = threadIdx.x;          // 0..127

    __shared__ float w_out_lds[G * H];   // q-layout, for the update phase
    __shared__ float w_out_p[G * HP];    // +1-padded copy for bit-loop reads
    __shared__ float hr0_lds[H];         // initial hrate (for J base)
    __shared__ float hrfin_lds[H];       // final hrate (for elig)
    __shared__ float feat[F];
    __shared__ float pf_lds[F];
    __shared__ float Iin_lds[H];
    __shared__ float C_lds[S * G];       // per-step spike-weight sums
    __shared__ float Jpart[16];          // J base partials
    __shared__ unsigned long long smask[2 * S];
    __shared__ float wob[G];
    __shared__ float vrate_lds[G];
    __shared__ float red[2];             // mean|I_in| reduce
    __shared__ float red2[2];            // hidden_active popcounts
    __shared__ float tdsh;

    // ---- issue all heavy global loads up front ----
    // W_in in update layout (q = t + 128k), held in registers for the session
    const float4* wi4 = (const float4*)(W_in_w + (size_t)b * (H * F));
    float4 winq0 = wi4[t];
    float4 winq1 = wi4[t + 128];
    float4 winq2 = wi4[t + 256];
    float4 winq3 = wi4[t + 384];
    const float wib = W_in_b[(size_t)b * H + t];

    float hv = hv_in[(size_t)b * H + t];
    float hu = hu_in[(size_t)b * H + t];
    float hr = hrate_in[(size_t)b * H + t];
    hr0_lds[t] = hr;

    float nz[S];
    #pragma unroll
    for (int s = 0; s < S; ++s)
        nz[s] = noise[((size_t)s * nB + b) * H + t];

    const float da = DA[b];

    // W_out: coalesced float4 stage + scatter into padded copy
    {
        float4 wv = ((const float4*)(W_out_w + (size_t)b * (G * H)))[t];
        ((float4*)w_out_lds)[t] = wv;
        int g  = t >> 5;
        int h0 = (t & 31) * 4;
        float* wp = w_out_p + g * HP + h0;
        wp[0] = wv.x; wp[1] = wv.y; wp[2] = wv.z; wp[3] = wv.w;
    }
    if (t < F) pf_lds[t] = prev_features[(size_t)b * F + t];
    if (t < G) wob[t]    = W_out_b[(size_t)b * G + t];

    // output-neuron state + td operands, prefetched into lane registers
    float vvv = 0.0f, vuu = 0.0f, vrr = 0.0f;
    int   gb  = 0;
    float rw  = 0.0f, Vprev = 0.0f;
    if (t < G) {
        vvv = vv_in[(size_t)b * G + t];
        vuu = vu_in[(size_t)b * G + t];
        vrr = vrate_in[(size_t)b * G + t];
        gb  = goal[b];
    }
    if (t == 0) {
        rw    = reward[b];
        Vprev = prev_values[(size_t)b * G + prev_goal[b]];
    }

    // ---- features (threads 0..15, one feature each) ----
    if (t < F) {
        float e = energy[b];
        float v;
        if      (t == 0)  v = e / 100.0f;
        else if (t == 1)  v = threat[b];
        else if (t == 2)  v = food_visible[b];
        else if (t == 3)  v = 1.0f - e / 100.0f;
        else if (t < 8)   v = (goal[b] == (t - 4)) ? 1.0f : 0.0f;
        else if (t < 13)  v = cls_probs[(size_t)b * 5 + (t - 8)];
        else if (t == 13) v = da;
        else if (t == 14) v = NA[b];
        else              v = fmaxf(0.0f, 0.5f - e / 100.0f);
        feat[t] = v;
    }
    __syncthreads();   // B1: feat ready

    // ---- I_in from register-held W_in (quad shfl_xor reassembly) ----
    // q = t + 128k -> row h = 32k + (t>>2), feature-quad j = t&3 (same all k)
    {
        const float4 fq = ((const float4*)feat)[t & 3];
        float d0 = winq0.x * fq.x + winq0.y * fq.y + winq0.z * fq.z + winq0.w * fq.w;
        float d1 = winq1.x * fq.x + winq1.y * fq.y + winq1.z * fq.z + winq1.w * fq.w;
        float d2 = winq2.x * fq.x + winq2.y * fq.y + winq2.z * fq.z + winq2.w * fq.w;
        float d3 = winq3.x * fq.x + winq3.y * fq.y + winq3.z * fq.z + winq3.w * fq.w;
        d0 += __shfl_xor(d0, 1); d0 += __shfl_xor(d0, 2);
        d1 += __shfl_xor(d1, 1); d1 += __shfl_xor(d1, 2);
        d2 += __shfl_xor(d2, 1); d2 += __shfl_xor(d2, 2);
        d3 += __shfl_xor(d3, 1); d3 += __shfl_xor(d3, 2);
        if ((t & 3) == 0) {
            int r = t >> 2;
            Iin_lds[r]      = d0;
            Iin_lds[r + 32] = d1;
            Iin_lds[r + 64] = d2;
            Iin_lds[r + 96] = d3;
        }
    }
    __syncthreads();   // B2: Iin_lds ready

    float Iraw = Iin_lds[t] + wib;
    float a = fabsf(Iraw);
    #pragma unroll
    for (int m = 32; m >= 1; m >>= 1) a += __shfl_xor(a, m, 64);
    if ((t & 63) == 0) red[t >> 6] = a;
    __syncthreads();   // B3: mean ready
    const float meanI = (red[0] + red[1]) * (1.0f / 128.0f);
    const float Iin = Iraw * (5.0f / (meanI + 1e-8f));

    // ---- 20 hidden substeps: pure VALU + one ballot per step ----
    float hsp = 0.0f;
    #pragma unroll
    for (int s = 0; s < S; ++s) {
        float I  = Iin + 0.3f * nz[s];
        float vn = hv + (0.04f * hv * hv + 5.0f * hv + 140.0f - hu + I);
        float un = hu + 0.02f * (0.2f * hv - hu);
        float sp = (vn >= 30.0f) ? 1.0f : 0.0f;
        hv = (sp > 0.0f) ? -65.0f : vn;
        hu = un + sp * 8.0f;
        hr = 0.9f * hr + 0.1f * sp;
        hsp += sp;
        unsigned long long mb = __ballot(sp > 0.0f);
        if ((t & 63) == 0) smask[2 * s + (t >> 6)] = mb;
    }
    hrfin_lds[t] = hr;
    {
        unsigned long long mb = __ballot(hsp > 0.0f);
        if ((t & 63) == 0) red2[t >> 6] = (float)__popcll(mb);
    }
    __syncthreads();   // B4: masks + hrfin + hr0 visible

    // ---- C[s][g] = sum of w[g][h] over spiking h (bit loops) ----
    if (t < S * G) {
        const int s = t >> 2;
        const int g = t & 3;
        const float* __restrict__ wr = w_out_p + g * HP;
        float acc = 0.0f;
        unsigned long long m0 = smask[2 * s];
        unsigned long long m1 = smask[2 * s + 1];
        while (m0) {
            int h = __builtin_ctzll(m0);
            m0 &= (m0 - 1);
            acc += wr[h];
        }
        while (m1) {
            int h = __builtin_ctzll(m1);
            m1 &= (m1 - 1);
            acc += wr[64 + h];
        }
        C_lds[t] = acc;
    } else if (t < S * G + 16) {
        // J base = W_out @ hrate_in, 16 threads x 32-element chunks
        const int u = t - S * G;
        const int g = u & 3;
        const int q = u >> 2;
        const float* __restrict__ wr = w_out_p + g * HP + q * 32;
        const float* __restrict__ h0 = hr0_lds + q * 32;
        float a0 = 0.0f, a1 = 0.0f, a2 = 0.0f, a3 = 0.0f;
        #pragma unroll
        for (int i = 0; i < 32; i += 4) {
            a0 = fmaf(wr[i + 0], h0[i + 0], a0);
            a1 = fmaf(wr[i + 1], h0[i + 1], a1);
            a2 = fmaf(wr[i + 2], h0[i + 2], a2);
            a3 = fmaf(wr[i + 3], h0[i + 3], a3);
        }
        Jpart[u] = (a0 + a1) + (a2 + a3);
    }
    __syncthreads();   // B5: C + Jpart ready

    // ---- output-neuron chain: 4 lanes, J recursion + izh ----
    if (t < G) {
        float J = (Jpart[t] + Jpart[t + 4]) + (Jpart[t + 8] + Jpart[t + 12]);
        const float wb = wob[t];
        #pragma unroll
        for (int s = 0; s < S; ++s) {
            J = 0.9f * J + 0.1f * C_lds[4 * s + t];
            float Ir = J + wb;
            float aa = fabsf(Ir);
            aa += __shfl_xor(aa, 1);
            aa += __shfl_xor(aa, 2);
            float m4 = 0.25f * aa;
            float Io = Ir * (4.0f / (m4 + 1e-8f));
            float vn = vvv + (0.04f * vvv * vvv + 5.0f * vvv + 140.0f - vuu + Io);
            float un = vuu + 0.02f * (0.2f * vvv - vuu);
            float sp = (vn >= 30.0f) ? 1.0f : 0.0f;
            vvv = (sp > 0.0f) ? -65.0f : vn;
            vuu = un + sp * 8.0f;
            vrr = 0.9f * vrr + 0.1f * sp;
        }
        vrate_lds[t] = vrr;
        float val = J + wb;                 // values == W@hr_final + b
        out_values[(size_t)b * G + t] = val;
        float vg = __shfl(val, gb, 4);      // lanes 0..3 all active
        if (t == 0) {
            float td = rw + 0.95f * vg - Vprev;
            out_td[b]     = td;
            out_hidden[b] = (red2[0] + red2[1]) * (1.0f / 128.0f);
            tdsh = td;
        }
    }
    __syncthreads();   // B6: tdsh + vrate ready

    const float td    = tdsh;
    const float scale = 1e-3f * td * da;
    const bool  upd   = fabsf(td) > 1e-3f;

    // ---- elig_in / W_in update: 512 float4s, W_in already in registers ----
    {
        const float4* ei4 = (const float4*)(elig_in + (size_t)b * (H * F));
        float4* oW = (float4*)(out_Win + (size_t)b * (H * F));
        float4* oE = (float4*)(out_ein + (size_t)b * (H * F));
        const float4* pf4 = (const float4*)pf_lds;
        const float4 pf = pf4[t & 3];
        float4 wq[4] = {winq0, winq1, winq2, winq3};
        #pragma unroll
        for (int k = 0; k < 4; ++k) {
            int q = t + 128 * k;
            int h = q >> 2;
            float4 e  = ei4[q];
            float  hrv = hrfin_lds[h];
            float4 en;
            en.x = 0.9f * e.x + hrv * pf.x;
            en.y = 0.9f * e.y + hrv * pf.y;
            en.z = 0.9f * e.z + hrv * pf.z;
            en.w = 0.9f * e.w + hrv * pf.w;
            oE[q] = en;
            float4 w = wq[k];
            float4 wn;
            if (upd) {
                wn.x = clip3(w.x + scale * en.x);
                wn.y = clip3(w.y + scale * en.y);
                wn.z = clip3(w.z + scale * en.z);
                wn.w = clip3(w.w + scale * en.w);
            } else {
                wn = w;
            }
            oW[q] = wn;
        }
    }

    // ---- elig_out / W_out update: 128 float4s ----
    {
        const float4* eo4 = (const float4*)(elig_out + (size_t)b * (G * H));
        float4* oW = (float4*)(out_Wout + (size_t)b * (G * H));
        float4* oE = (float4*)(out_eout + (size_t)b * (G * H));
        int q  = t;
        int gg = q >> 5;
        int h0 = (q & 31) * 4;
        float4 e  = eo4[q];
        float  vrv = vrate_lds[gg];
        float4 en;
        en.x = 0.9f * e.x + vrv * hrfin_lds[h0 + 0];
        en.y = 0.9f * e.y + vrv * hrfin_lds[h0 + 1];
        en.z = 0.9f * e.z + vrv * hrfin_lds[h0 + 2];
        en.w = 0.9f * e.w + vrv * hrfin_lds[h0 + 3];
        oE[q] = en;
        float4 w = ((const float4*)w_out_lds)[q];
        float4 wn;
        if (upd) {
            wn.x = clip3(w.x + scale * en.x);
            wn.y = clip3(w.y + scale * en.y);
            wn.z = clip3(w.z + scale * en.z);
            wn.w = clip3(w.w + scale * en.w);
        } else {
            wn = w;
        }
        oW[q] = wn;
    }
}

} // namespace

extern "C" void kernel_launch(void* const* d_in, const int* in_sizes, int n_in,
                              void* d_out, int out_size, void* d_ws, size_t ws_size,
                              hipStream_t stream) {
    const int nB = in_sizes[0];          // 8192

    float* out        = (float*)d_out;   // outputs concatenated flat
    float* out_values = out;
    float* out_td     = out_values + (size_t)nB * G;
    float* out_hidden = out_td + nB;
    float* out_Win    = out_hidden + nB;
    float* out_Wout   = out_Win + (size_t)nB * H * F;
    float* out_ein    = out_Wout + (size_t)nB * G * H;
    float* out_eout   = out_ein + (size_t)nB * H * F;

    spiking_critic_kernel<<<dim3(nB), dim3(128), 0, stream>>>(
        (const float*)d_in[0],  (const float*)d_in[1],  (const float*)d_in[2],
        (const int*)  d_in[3],  (const int*)  d_in[4],
        (const float*)d_in[5],  (const float*)d_in[6],  (const float*)d_in[7],
        (const float*)d_in[8],  (const float*)d_in[9],  (const float*)d_in[10],
        (const float*)d_in[11], (const float*)d_in[12], (const float*)d_in[13],
        (const float*)d_in[14], (const float*)d_in[15], (const float*)d_in[16],
        (const float*)d_in[17], (const float*)d_in[18], (const float*)d_in[19],
        (const float*)d_in[20], (const float*)d_in[21], (const float*)d_in[22],
        (const float*)d_in[23],
        out_values, out_td, out_hidden, out_Win, out_Wout, out_ein, out_eout,
        nB);
}

// Round 5
// 393.163 us; speedup vs baseline: 1.0119x; 1.0119x over previous
//
#include <hip/hip_runtime.h>

// One workgroup (128 threads, 2 waves) per batch element b.
// v6 = v3 (the passing 127us kernel) + ONE structural change: elig_in /
// elig_out are prefetched into registers at the TOP of the kernel instead
// of being loaded after the final barrier (which exposed a full HBM
// round-trip per block at the tail). v4/v5's failure was traced to the
// divergent cls_probs shuffle in the rewritten feature block; that whole
// rewrite is reverted — the feature block below is verbatim v3.

namespace {

constexpr int F = 16;
constexpr int H = 128;
constexpr int G = 4;
constexpr int S = 20;
constexpr int HP = H + 1;   // padded W_out row stride for bit-loop reads

__device__ __forceinline__ float clip3(float x) {
    return fminf(fmaxf(x, -3.0f), 3.0f);
}

__global__ __launch_bounds__(128)
void spiking_critic_kernel(
    const float* __restrict__ energy,
    const float* __restrict__ threat,
    const float* __restrict__ food_visible,
    const int*   __restrict__ goal,
    const int*   __restrict__ prev_goal,
    const float* __restrict__ DA,
    const float* __restrict__ NA,
    const float* __restrict__ reward,
    const float* __restrict__ cls_probs,
    const float* __restrict__ W_in_w,
    const float* __restrict__ W_in_b,
    const float* __restrict__ W_out_w,
    const float* __restrict__ W_out_b,
    const float* __restrict__ hv_in,
    const float* __restrict__ hu_in,
    const float* __restrict__ hrate_in,
    const float* __restrict__ vv_in,
    const float* __restrict__ vu_in,
    const float* __restrict__ vrate_in,
    const float* __restrict__ elig_in,
    const float* __restrict__ elig_out,
    const float* __restrict__ prev_values,
    const float* __restrict__ prev_features,
    const float* __restrict__ noise,
    float* __restrict__ out_values,
    float* __restrict__ out_td,
    float* __restrict__ out_hidden,
    float* __restrict__ out_Win,
    float* __restrict__ out_Wout,
    float* __restrict__ out_ein,
    float* __restrict__ out_eout,
    int nB)
{
    const int b = blockIdx.x;
    const int t = threadIdx.x;          // 0..127

    __shared__ float w_out_lds[G * H];   // q-layout, for the update phase
    __shared__ float w_out_p[G * HP];    // +1-padded copy for bit-loop reads
    __shared__ float hr0_lds[H];         // initial hrate (for J base)
    __shared__ float hrfin_lds[H];       // final hrate (for elig)
    __shared__ float feat[F];
    __shared__ float pf_lds[F];
    __shared__ float Iin_lds[H];
    __shared__ float C_lds[S * G];       // per-step spike-weight sums
    __shared__ float Jpart[16];          // J base partials
    __shared__ unsigned long long smask[2 * S];
    __shared__ float wob[G];
    __shared__ float vrate_lds[G];
    __shared__ float red[2];             // mean|I_in| reduce
    __shared__ float red2[2];            // hidden_active popcounts
    __shared__ float tdsh;

    // ---- issue all heavy global loads up front ----
    // W_in in update layout (q = t + 128k), held in registers for the session
    const float4* wi4 = (const float4*)(W_in_w + (size_t)b * (H * F));
    float4 winq0 = wi4[t];
    float4 winq1 = wi4[t + 128];
    float4 winq2 = wi4[t + 256];
    float4 winq3 = wi4[t + 384];
    const float wib = W_in_b[(size_t)b * H + t];

    float hv = hv_in[(size_t)b * H + t];
    float hu = hu_in[(size_t)b * H + t];
    float hr = hrate_in[(size_t)b * H + t];
    hr0_lds[t] = hr;

    float nz[S];
    #pragma unroll
    for (int s = 0; s < S; ++s)
        nz[s] = noise[((size_t)s * nB + b) * H + t];

    // NEW in v6: elig prefetch into registers — previously loaded after the
    // final barrier, exposing a full HBM round-trip per block at the tail.
    const float4* ei4p = (const float4*)(elig_in  + (size_t)b * (H * F));
    const float4 ei0 = ei4p[t];
    const float4 ei1 = ei4p[t + 128];
    const float4 ei2 = ei4p[t + 256];
    const float4 ei3 = ei4p[t + 384];
    const float4 eo  = ((const float4*)(elig_out + (size_t)b * (G * H)))[t];

    const float da = DA[b];

    // W_out: coalesced float4 stage + scatter into padded copy
    {
        float4 wv = ((const float4*)(W_out_w + (size_t)b * (G * H)))[t];
        ((float4*)w_out_lds)[t] = wv;
        int g  = t >> 5;
        int h0 = (t & 31) * 4;
        float* wp = w_out_p + g * HP + h0;
        wp[0] = wv.x; wp[1] = wv.y; wp[2] = wv.z; wp[3] = wv.w;
    }
    if (t < F) pf_lds[t] = prev_features[(size_t)b * F + t];
    if (t < G) wob[t]    = W_out_b[(size_t)b * G + t];

    // output-neuron state + td operands, prefetched into lane registers
    float vvv = 0.0f, vuu = 0.0f, vrr = 0.0f;
    int   gb  = 0;
    float rw  = 0.0f, Vprev = 0.0f;
    if (t < G) {
        vvv = vv_in[(size_t)b * G + t];
        vuu = vu_in[(size_t)b * G + t];
        vrr = vrate_in[(size_t)b * G + t];
        gb  = goal[b];
    }
    if (t == 0) {
        rw    = reward[b];
        Vprev = prev_values[(size_t)b * G + prev_goal[b]];
    }

    // ---- features (threads 0..15, one feature each) — verbatim v3 ----
    if (t < F) {
        float e = energy[b];
        float v;
        if      (t == 0)  v = e / 100.0f;
        else if (t == 1)  v = threat[b];
        else if (t == 2)  v = food_visible[b];
        else if (t == 3)  v = 1.0f - e / 100.0f;
        else if (t < 8)   v = (goal[b] == (t - 4)) ? 1.0f : 0.0f;
        else if (t < 13)  v = cls_probs[(size_t)b * 5 + (t - 8)];
        else if (t == 13) v = da;
        else if (t == 14) v = NA[b];
        else              v = fmaxf(0.0f, 0.5f - e / 100.0f);
        feat[t] = v;
    }
    __syncthreads();   // B1: feat ready

    // ---- I_in from register-held W_in (quad shfl_xor reassembly) ----
    // q = t + 128k -> row h = 32k + (t>>2), feature-quad j = t&3 (same all k)
    {
        const float4 fq = ((const float4*)feat)[t & 3];
        float d0 = winq0.x * fq.x + winq0.y * fq.y + winq0.z * fq.z + winq0.w * fq.w;
        float d1 = winq1.x * fq.x + winq1.y * fq.y + winq1.z * fq.z + winq1.w * fq.w;
        float d2 = winq2.x * fq.x + winq2.y * fq.y + winq2.z * fq.z + winq2.w * fq.w;
        float d3 = winq3.x * fq.x + winq3.y * fq.y + winq3.z * fq.z + winq3.w * fq.w;
        d0 += __shfl_xor(d0, 1); d0 += __shfl_xor(d0, 2);
        d1 += __shfl_xor(d1, 1); d1 += __shfl_xor(d1, 2);
        d2 += __shfl_xor(d2, 1); d2 += __shfl_xor(d2, 2);
        d3 += __shfl_xor(d3, 1); d3 += __shfl_xor(d3, 2);
        if ((t & 3) == 0) {
            int r = t >> 2;
            Iin_lds[r]      = d0;
            Iin_lds[r + 32] = d1;
            Iin_lds[r + 64] = d2;
            Iin_lds[r + 96] = d3;
        }
    }
    __syncthreads();   // B2: Iin_lds ready

    float Iraw = Iin_lds[t] + wib;
    float a = fabsf(Iraw);
    #pragma unroll
    for (int m = 32; m >= 1; m >>= 1) a += __shfl_xor(a, m, 64);
    if ((t & 63) == 0) red[t >> 6] = a;
    __syncthreads();   // B3: mean ready
    const float meanI = (red[0] + red[1]) * (1.0f / 128.0f);
    const float Iin = Iraw * (5.0f / (meanI + 1e-8f));

    // ---- 20 hidden substeps: pure VALU + one ballot per step ----
    float hsp = 0.0f;
    #pragma unroll
    for (int s = 0; s < S; ++s) {
        float I  = Iin + 0.3f * nz[s];
        float vn = hv + (0.04f * hv * hv + 5.0f * hv + 140.0f - hu + I);
        float un = hu + 0.02f * (0.2f * hv - hu);
        float sp = (vn >= 30.0f) ? 1.0f : 0.0f;
        hv = (sp > 0.0f) ? -65.0f : vn;
        hu = un + sp * 8.0f;
        hr = 0.9f * hr + 0.1f * sp;
        hsp += sp;
        unsigned long long mb = __ballot(sp > 0.0f);
        if ((t & 63) == 0) smask[2 * s + (t >> 6)] = mb;
    }
    hrfin_lds[t] = hr;
    {
        unsigned long long mb = __ballot(hsp > 0.0f);
        if ((t & 63) == 0) red2[t >> 6] = (float)__popcll(mb);
    }
    __syncthreads();   // B4: masks + hrfin + hr0 visible

    // ---- C[s][g] = sum of w[g][h] over spiking h (bit loops) ----
    if (t < S * G) {
        const int s = t >> 2;
        const int g = t & 3;
        const float* __restrict__ wr = w_out_p + g * HP;
        float acc = 0.0f;
        unsigned long long m0 = smask[2 * s];
        unsigned long long m1 = smask[2 * s + 1];
        while (m0) {
            int h = __builtin_ctzll(m0);
            m0 &= (m0 - 1);
            acc += wr[h];
        }
        while (m1) {
            int h = __builtin_ctzll(m1);
            m1 &= (m1 - 1);
            acc += wr[64 + h];
        }
        C_lds[t] = acc;
    } else if (t < S * G + 16) {
        // J base = W_out @ hrate_in, 16 threads x 32-element chunks
        const int u = t - S * G;
        const int g = u & 3;
        const int q = u >> 2;
        const float* __restrict__ wr = w_out_p + g * HP + q * 32;
        const float* __restrict__ h0 = hr0_lds + q * 32;
        float a0 = 0.0f, a1 = 0.0f, a2 = 0.0f, a3 = 0.0f;
        #pragma unroll
        for (int i = 0; i < 32; i += 4) {
            a0 = fmaf(wr[i + 0], h0[i + 0], a0);
            a1 = fmaf(wr[i + 1], h0[i + 1], a1);
            a2 = fmaf(wr[i + 2], h0[i + 2], a2);
            a3 = fmaf(wr[i + 3], h0[i + 3], a3);
        }
        Jpart[u] = (a0 + a1) + (a2 + a3);
    }
    __syncthreads();   // B5: C + Jpart ready

    // ---- output-neuron chain: 4 lanes, J recursion + izh ----
    if (t < G) {
        float J = (Jpart[t] + Jpart[t + 4]) + (Jpart[t + 8] + Jpart[t + 12]);
        const float wb = wob[t];
        #pragma unroll
        for (int s = 0; s < S; ++s) {
            J = 0.9f * J + 0.1f * C_lds[4 * s + t];
            float Ir = J + wb;
            float aa = fabsf(Ir);
            aa += __shfl_xor(aa, 1);
            aa += __shfl_xor(aa, 2);
            float m4 = 0.25f * aa;
            float Io = Ir * (4.0f / (m4 + 1e-8f));
            float vn = vvv + (0.04f * vvv * vvv + 5.0f * vvv + 140.0f - vuu + Io);
            float un = vuu + 0.02f * (0.2f * vvv - vuu);
            float sp = (vn >= 30.0f) ? 1.0f : 0.0f;
            vvv = (sp > 0.0f) ? -65.0f : vn;
            vuu = un + sp * 8.0f;
            vrr = 0.9f * vrr + 0.1f * sp;
        }
        vrate_lds[t] = vrr;
        float val = J + wb;                 // values == W@hr_final + b
        out_values[(size_t)b * G + t] = val;
        float vg = __shfl(val, gb, 4);      // lanes 0..3 all active
        if (t == 0) {
            float td = rw + 0.95f * vg - Vprev;
            out_td[b]     = td;
            out_hidden[b] = (red2[0] + red2[1]) * (1.0f / 128.0f);
            tdsh = td;
        }
    }
    __syncthreads();   // B6: tdsh + vrate ready

    const float td    = tdsh;
    const float scale = 1e-3f * td * da;
    const bool  upd   = fabsf(td) > 1e-3f;

    // ---- elig_in / W_in update: all data already in registers ----
    {
        float4* oW = (float4*)(out_Win + (size_t)b * (H * F));
        float4* oE = (float4*)(out_ein + (size_t)b * (H * F));
        const float4* pf4 = (const float4*)pf_lds;
        const float4 pf = pf4[t & 3];
        float4 wq[4] = {winq0, winq1, winq2, winq3};
        float4 eq[4] = {ei0, ei1, ei2, ei3};
        #pragma unroll
        for (int k = 0; k < 4; ++k) {
            int q = t + 128 * k;
            int h = q >> 2;
            float4 e  = eq[k];
            float  hrv = hrfin_lds[h];
            float4 en;
            en.x = 0.9f * e.x + hrv * pf.x;
            en.y = 0.9f * e.y + hrv * pf.y;
            en.z = 0.9f * e.z + hrv * pf.z;
            en.w = 0.9f * e.w + hrv * pf.w;
            oE[q] = en;
            float4 w = wq[k];
            float4 wn;
            if (upd) {
                wn.x = clip3(w.x + scale * en.x);
                wn.y = clip3(w.y + scale * en.y);
                wn.z = clip3(w.z + scale * en.z);
                wn.w = clip3(w.w + scale * en.w);
            } else {
                wn = w;
            }
            oW[q] = wn;
        }
    }

    // ---- elig_out / W_out update: 128 float4s ----
    {
        float4* oW = (float4*)(out_Wout + (size_t)b * (G * H));
        float4* oE = (float4*)(out_eout + (size_t)b * (G * H));
        int q  = t;
        int gg = q >> 5;
        int h0 = (q & 31) * 4;
        float  vrv = vrate_lds[gg];
        float4 en;
        en.x = 0.9f * eo.x + vrv * hrfin_lds[h0 + 0];
        en.y = 0.9f * eo.y + vrv * hrfin_lds[h0 + 1];
        en.z = 0.9f * eo.z + vrv * hrfin_lds[h0 + 2];
        en.w = 0.9f * eo.w + vrv * hrfin_lds[h0 + 3];
        oE[q] = en;
        float4 w = ((const float4*)w_out_lds)[q];
        float4 wn;
        if (upd) {
            wn.x = clip3(w.x + scale * en.x);
            wn.y = clip3(w.y + scale * en.y);
            wn.z = clip3(w.z + scale * en.z);
            wn.w = clip3(w.w + scale * en.w);
        } else {
            wn = w;
        }
        oW[q] = wn;
    }
}

} // namespace

extern "C" void kernel_launch(void* const* d_in, const int* in_sizes, int n_in,
                              void* d_out, int out_size, void* d_ws, size_t ws_size,
                              hipStream_t stream) {
    const int nB = in_sizes[0];          // 8192

    float* out        = (float*)d_out;   // outputs concatenated flat
    float* out_values = out;
    float* out_td     = out_values + (size_t)nB * G;
    float* out_hidden = out_td + nB;
    float* out_Win    = out_hidden + nB;
    float* out_Wout   = out_Win + (size_t)nB * H * F;
    float* out_ein    = out_Wout + (size_t)nB * G * H;
    float* out_eout   = out_ein + (size_t)nB * H * F;

    spiking_critic_kernel<<<dim3(nB), dim3(128), 0, stream>>>(
        (const float*)d_in[0],  (const float*)d_in[1],  (const float*)d_in[2],
        (const int*)  d_in[3],  (const int*)  d_in[4],
        (const float*)d_in[5],  (const float*)d_in[6],  (const float*)d_in[7],
        (const float*)d_in[8],  (const float*)d_in[9],  (const float*)d_in[10],
        (const float*)d_in[11], (const float*)d_in[12], (const float*)d_in[13],
        (const float*)d_in[14], (const float*)d_in[15], (const float*)d_in[16],
        (const float*)d_in[17], (const float*)d_in[18], (const float*)d_in[19],
        (const float*)d_in[20], (const float*)d_in[21], (const float*)d_in[22],
        (const float*)d_in[23],
        out_values, out_td, out_hidden, out_Win, out_Wout, out_ein, out_eout,
        nB);
}

// Round 6
// 390.127 us; speedup vs baseline: 1.0198x; 1.0078x over previous
//
#include <hip/hip_runtime.h>

// One workgroup (128 threads, 2 waves) per batch element b.
// v7 = v3 (the passing 127us kernel) + elig_in/elig_out prefetched into
// registers, issued LAST of all loads, immediately before barrier B1.
// v6 issued them too early: vmcnt is an IN-ORDER counter, so the W_out
// scatter and feat[] stores (which wait on later-issued loads) drained the
// whole 25KB elig stream before B1 -> head-serialized, 146us. Issuing them
// newest means every intermediate wait is a counted vmcnt(6) that leaves
// them in flight; they land during the B1..B6 compute phase and the update
// phase reads registers with zero exposed latency (v3 paid a full HBM
// round-trip at the tail instead).

namespace {

constexpr int F = 16;
constexpr int H = 128;
constexpr int G = 4;
constexpr int S = 20;
constexpr int HP = H + 1;   // padded W_out row stride for bit-loop reads

__device__ __forceinline__ float clip3(float x) {
    return fminf(fmaxf(x, -3.0f), 3.0f);
}

__global__ __launch_bounds__(128)
void spiking_critic_kernel(
    const float* __restrict__ energy,
    const float* __restrict__ threat,
    const float* __restrict__ food_visible,
    const int*   __restrict__ goal,
    const int*   __restrict__ prev_goal,
    const float* __restrict__ DA,
    const float* __restrict__ NA,
    const float* __restrict__ reward,
    const float* __restrict__ cls_probs,
    const float* __restrict__ W_in_w,
    const float* __restrict__ W_in_b,
    const float* __restrict__ W_out_w,
    const float* __restrict__ W_out_b,
    const float* __restrict__ hv_in,
    const float* __restrict__ hu_in,
    const float* __restrict__ hrate_in,
    const float* __restrict__ vv_in,
    const float* __restrict__ vu_in,
    const float* __restrict__ vrate_in,
    const float* __restrict__ elig_in,
    const float* __restrict__ elig_out,
    const float* __restrict__ prev_values,
    const float* __restrict__ prev_features,
    const float* __restrict__ noise,
    float* __restrict__ out_values,
    float* __restrict__ out_td,
    float* __restrict__ out_hidden,
    float* __restrict__ out_Win,
    float* __restrict__ out_Wout,
    float* __restrict__ out_ein,
    float* __restrict__ out_eout,
    int nB)
{
    const int b = blockIdx.x;
    const int t = threadIdx.x;          // 0..127

    __shared__ float w_out_lds[G * H];   // q-layout, for the update phase
    __shared__ float w_out_p[G * HP];    // +1-padded copy for bit-loop reads
    __shared__ float hr0_lds[H];         // initial hrate (for J base)
    __shared__ float hrfin_lds[H];       // final hrate (for elig)
    __shared__ float feat[F];
    __shared__ float pf_lds[F];
    __shared__ float Iin_lds[H];
    __shared__ float C_lds[S * G];       // per-step spike-weight sums
    __shared__ float Jpart[16];          // J base partials
    __shared__ unsigned long long smask[2 * S];
    __shared__ float wob[G];
    __shared__ float vrate_lds[G];
    __shared__ float red[2];             // mean|I_in| reduce
    __shared__ float red2[2];            // hidden_active popcounts
    __shared__ float tdsh;

    // ---- issue heavy global loads up front (v3 order) ----
    // W_in in update layout (q = t + 128k), held in registers for the session
    const float4* wi4 = (const float4*)(W_in_w + (size_t)b * (H * F));
    float4 winq0 = wi4[t];
    float4 winq1 = wi4[t + 128];
    float4 winq2 = wi4[t + 256];
    float4 winq3 = wi4[t + 384];
    const float wib = W_in_b[(size_t)b * H + t];

    float hv = hv_in[(size_t)b * H + t];
    float hu = hu_in[(size_t)b * H + t];
    float hr = hrate_in[(size_t)b * H + t];
    hr0_lds[t] = hr;

    float nz[S];
    #pragma unroll
    for (int s = 0; s < S; ++s)
        nz[s] = noise[((size_t)s * nB + b) * H + t];

    const float da = DA[b];

    // W_out: coalesced float4 stage + scatter into padded copy
    {
        float4 wv = ((const float4*)(W_out_w + (size_t)b * (G * H)))[t];
        ((float4*)w_out_lds)[t] = wv;
        int g  = t >> 5;
        int h0 = (t & 31) * 4;
        float* wp = w_out_p + g * HP + h0;
        wp[0] = wv.x; wp[1] = wv.y; wp[2] = wv.z; wp[3] = wv.w;
    }
    if (t < F) pf_lds[t] = prev_features[(size_t)b * F + t];
    if (t < G) wob[t]    = W_out_b[(size_t)b * G + t];

    // output-neuron state + td operands, prefetched into lane registers
    float vvv = 0.0f, vuu = 0.0f, vrr = 0.0f;
    int   gb  = 0;
    float rw  = 0.0f, Vprev = 0.0f;
    if (t < G) {
        vvv = vv_in[(size_t)b * G + t];
        vuu = vu_in[(size_t)b * G + t];
        vrr = vrate_in[(size_t)b * G + t];
        gb  = goal[b];
    }
    if (t == 0) {
        rw    = reward[b];
        Vprev = prev_values[(size_t)b * G + prev_goal[b]];
    }

    // ---- features (threads 0..15, one feature each) — verbatim v3 ----
    if (t < F) {
        float e = energy[b];
        float v;
        if      (t == 0)  v = e / 100.0f;
        else if (t == 1)  v = threat[b];
        else if (t == 2)  v = food_visible[b];
        else if (t == 3)  v = 1.0f - e / 100.0f;
        else if (t < 8)   v = (goal[b] == (t - 4)) ? 1.0f : 0.0f;
        else if (t < 13)  v = cls_probs[(size_t)b * 5 + (t - 8)];
        else if (t == 13) v = da;
        else if (t == 14) v = NA[b];
        else              v = fmaxf(0.0f, 0.5f - e / 100.0f);
        feat[t] = v;
    }

    // ---- elig prefetch: issued LAST, newest in the vmcnt queue ----
    // Consumed only after B6; every intermediate wait can leave these 6
    // loads in flight (counted vmcnt), so their latency hides under the
    // entire compute phase.
    const float4* ei4p = (const float4*)(elig_in  + (size_t)b * (H * F));
    const float4 ei0 = ei4p[t];
    const float4 ei1 = ei4p[t + 128];
    const float4 ei2 = ei4p[t + 256];
    const float4 ei3 = ei4p[t + 384];
    const float4 eo  = ((const float4*)(elig_out + (size_t)b * (G * H)))[t];

    __syncthreads();   // B1: feat ready

    // ---- I_in from register-held W_in (quad shfl_xor reassembly) ----
    // q = t + 128k -> row h = 32k + (t>>2), feature-quad j = t&3 (same all k)
    {
        const float4 fq = ((const float4*)feat)[t & 3];
        float d0 = winq0.x * fq.x + winq0.y * fq.y + winq0.z * fq.z + winq0.w * fq.w;
        float d1 = winq1.x * fq.x + winq1.y * fq.y + winq1.z * fq.z + winq1.w * fq.w;
        float d2 = winq2.x * fq.x + winq2.y * fq.y + winq2.z * fq.z + winq2.w * fq.w;
        float d3 = winq3.x * fq.x + winq3.y * fq.y + winq3.z * fq.z + winq3.w * fq.w;
        d0 += __shfl_xor(d0, 1); d0 += __shfl_xor(d0, 2);
        d1 += __shfl_xor(d1, 1); d1 += __shfl_xor(d1, 2);
        d2 += __shfl_xor(d2, 1); d2 += __shfl_xor(d2, 2);
        d3 += __shfl_xor(d3, 1); d3 += __shfl_xor(d3, 2);
        if ((t & 3) == 0) {
            int r = t >> 2;
            Iin_lds[r]      = d0;
            Iin_lds[r + 32] = d1;
            Iin_lds[r + 64] = d2;
            Iin_lds[r + 96] = d3;
        }
    }
    __syncthreads();   // B2: Iin_lds ready

    float Iraw = Iin_lds[t] + wib;
    float a = fabsf(Iraw);
    #pragma unroll
    for (int m = 32; m >= 1; m >>= 1) a += __shfl_xor(a, m, 64);
    if ((t & 63) == 0) red[t >> 6] = a;
    __syncthreads();   // B3: mean ready
    const float meanI = (red[0] + red[1]) * (1.0f / 128.0f);
    const float Iin = Iraw * (5.0f / (meanI + 1e-8f));

    // ---- 20 hidden substeps: pure VALU + one ballot per step ----
    float hsp = 0.0f;
    #pragma unroll
    for (int s = 0; s < S; ++s) {
        float I  = Iin + 0.3f * nz[s];
        float vn = hv + (0.04f * hv * hv + 5.0f * hv + 140.0f - hu + I);
        float un = hu + 0.02f * (0.2f * hv - hu);
        float sp = (vn >= 30.0f) ? 1.0f : 0.0f;
        hv = (sp > 0.0f) ? -65.0f : vn;
        hu = un + sp * 8.0f;
        hr = 0.9f * hr + 0.1f * sp;
        hsp += sp;
        unsigned long long mb = __ballot(sp > 0.0f);
        if ((t & 63) == 0) smask[2 * s + (t >> 6)] = mb;
    }
    hrfin_lds[t] = hr;
    {
        unsigned long long mb = __ballot(hsp > 0.0f);
        if ((t & 63) == 0) red2[t >> 6] = (float)__popcll(mb);
    }
    __syncthreads();   // B4: masks + hrfin + hr0 visible

    // ---- C[s][g] = sum of w[g][h] over spiking h (bit loops) ----
    if (t < S * G) {
        const int s = t >> 2;
        const int g = t & 3;
        const float* __restrict__ wr = w_out_p + g * HP;
        float acc = 0.0f;
        unsigned long long m0 = smask[2 * s];
        unsigned long long m1 = smask[2 * s + 1];
        while (m0) {
            int h = __builtin_ctzll(m0);
            m0 &= (m0 - 1);
            acc += wr[h];
        }
        while (m1) {
            int h = __builtin_ctzll(m1);
            m1 &= (m1 - 1);
            acc += wr[64 + h];
        }
        C_lds[t] = acc;
    } else if (t < S * G + 16) {
        // J base = W_out @ hrate_in, 16 threads x 32-element chunks
        const int u = t - S * G;
        const int g = u & 3;
        const int q = u >> 2;
        const float* __restrict__ wr = w_out_p + g * HP + q * 32;
        const float* __restrict__ h0 = hr0_lds + q * 32;
        float a0 = 0.0f, a1 = 0.0f, a2 = 0.0f, a3 = 0.0f;
        #pragma unroll
        for (int i = 0; i < 32; i += 4) {
            a0 = fmaf(wr[i + 0], h0[i + 0], a0);
            a1 = fmaf(wr[i + 1], h0[i + 1], a1);
            a2 = fmaf(wr[i + 2], h0[i + 2], a2);
            a3 = fmaf(wr[i + 3], h0[i + 3], a3);
        }
        Jpart[u] = (a0 + a1) + (a2 + a3);
    }
    __syncthreads();   // B5: C + Jpart ready

    // ---- output-neuron chain: 4 lanes, J recursion + izh ----
    if (t < G) {
        float J = (Jpart[t] + Jpart[t + 4]) + (Jpart[t + 8] + Jpart[t + 12]);
        const float wb = wob[t];
        #pragma unroll
        for (int s = 0; s < S; ++s) {
            J = 0.9f * J + 0.1f * C_lds[4 * s + t];
            float Ir = J + wb;
            float aa = fabsf(Ir);
            aa += __shfl_xor(aa, 1);
            aa += __shfl_xor(aa, 2);
            float m4 = 0.25f * aa;
            float Io = Ir * (4.0f / (m4 + 1e-8f));
            float vn = vvv + (0.04f * vvv * vvv + 5.0f * vvv + 140.0f - vuu + Io);
            float un = vuu + 0.02f * (0.2f * vvv - vuu);
            float sp = (vn >= 30.0f) ? 1.0f : 0.0f;
            vvv = (sp > 0.0f) ? -65.0f : vn;
            vuu = un + sp * 8.0f;
            vrr = 0.9f * vrr + 0.1f * sp;
        }
        vrate_lds[t] = vrr;
        float val = J + wb;                 // values == W@hr_final + b
        out_values[(size_t)b * G + t] = val;
        float vg = __shfl(val, gb, 4);      // lanes 0..3 all active
        if (t == 0) {
            float td = rw + 0.95f * vg - Vprev;
            out_td[b]     = td;
            out_hidden[b] = (red2[0] + red2[1]) * (1.0f / 128.0f);
            tdsh = td;
        }
    }
    __syncthreads();   // B6: tdsh + vrate ready

    const float td    = tdsh;
    const float scale = 1e-3f * td * da;
    const bool  upd   = fabsf(td) > 1e-3f;

    // ---- elig_in / W_in update: all data already in registers ----
    {
        float4* oW = (float4*)(out_Win + (size_t)b * (H * F));
        float4* oE = (float4*)(out_ein + (size_t)b * (H * F));
        const float4* pf4 = (const float4*)pf_lds;
        const float4 pf = pf4[t & 3];
        float4 wq[4] = {winq0, winq1, winq2, winq3};
        float4 eq[4] = {ei0, ei1, ei2, ei3};
        #pragma unroll
        for (int k = 0; k < 4; ++k) {
            int q = t + 128 * k;
            int h = q >> 2;
            float4 e  = eq[k];
            float  hrv = hrfin_lds[h];
            float4 en;
            en.x = 0.9f * e.x + hrv * pf.x;
            en.y = 0.9f * e.y + hrv * pf.y;
            en.z = 0.9f * e.z + hrv * pf.z;
            en.w = 0.9f * e.w + hrv * pf.w;
            oE[q] = en;
            float4 w = wq[k];
            float4 wn;
            if (upd) {
                wn.x = clip3(w.x + scale * en.x);
                wn.y = clip3(w.y + scale * en.y);
                wn.z = clip3(w.z + scale * en.z);
                wn.w = clip3(w.w + scale * en.w);
            } else {
                wn = w;
            }
            oW[q] = wn;
        }
    }

    // ---- elig_out / W_out update: 128 float4s ----
    {
        float4* oW = (float4*)(out_Wout + (size_t)b * (G * H));
        float4* oE = (float4*)(out_eout + (size_t)b * (G * H));
        int q  = t;
        int gg = q >> 5;
        int h0 = (q & 31) * 4;
        float  vrv = vrate_lds[gg];
        float4 en;
        en.x = 0.9f * eo.x + vrv * hrfin_lds[h0 + 0];
        en.y = 0.9f * eo.y + vrv * hrfin_lds[h0 + 1];
        en.z = 0.9f * eo.z + vrv * hrfin_lds[h0 + 2];
        en.w = 0.9f * eo.w + vrv * hrfin_lds[h0 + 3];
        oE[q] = en;
        float4 w = ((const float4*)w_out_lds)[q];
        float4 wn;
        if (upd) {
            wn.x = clip3(w.x + scale * en.x);
            wn.y = clip3(w.y + scale * en.y);
            wn.z = clip3(w.z + scale * en.z);
            wn.w = clip3(w.w + scale * en.w);
        } else {
            wn = w;
        }
        oW[q] = wn;
    }
}

} // namespace

extern "C" void kernel_launch(void* const* d_in, const int* in_sizes, int n_in,
                              void* d_out, int out_size, void* d_ws, size_t ws_size,
                              hipStream_t stream) {
    const int nB = in_sizes[0];          // 8192

    float* out        = (float*)d_out;   // outputs concatenated flat
    float* out_values = out;
    float* out_td     = out_values + (size_t)nB * G;
    float* out_hidden = out_td + nB;
    float* out_Win    = out_hidden + nB;
    float* out_Wout   = out_Win + (size_t)nB * H * F;
    float* out_ein    = out_Wout + (size_t)nB * G * H;
    float* out_eout   = out_ein + (size_t)nB * H * F;

    spiking_critic_kernel<<<dim3(nB), dim3(128), 0, stream>>>(
        (const float*)d_in[0],  (const float*)d_in[1],  (const float*)d_in[2],
        (const int*)  d_in[3],  (const int*)  d_in[4],
        (const float*)d_in[5],  (const float*)d_in[6],  (const float*)d_in[7],
        (const float*)d_in[8],  (const float*)d_in[9],  (const float*)d_in[10],
        (const float*)d_in[11], (const float*)d_in[12], (const float*)d_in[13],
        (const float*)d_in[14], (const float*)d_in[15], (const float*)d_in[16],
        (const float*)d_in[17], (const float*)d_in[18], (const float*)d_in[19],
        (const float*)d_in[20], (const float*)d_in[21], (const float*)d_in[22],
        (const float*)d_in[23],
        out_values, out_td, out_hidden, out_Win, out_Wout, out_ein, out_eout,
        nB);
}